// Round 1
// baseline (672.656 us; speedup 1.0000x reference)
//
#include <hip/hip_runtime.h>
#include <stdint.h>

typedef unsigned short u16;
typedef __bf16 bf16x8 __attribute__((ext_vector_type(8)));
typedef float  f32x4  __attribute__((ext_vector_type(4)));

#define MFMA16(a,b,c) __builtin_amdgcn_mfma_f32_16x16x32_bf16((a),(b),(c),0,0,0)

// B=32, N=512, C=1024, H=16, HD=64; SCALE = 1/8
// bf16 round-to-nearest-even
__device__ __forceinline__ u16 f2b(float f) {
  unsigned int u = __builtin_bit_cast(unsigned int, f);
  u += 0x7fffu + ((u >> 16) & 1u);
  return (u16)(u >> 16);
}

// ------------------------------------------------------------------
// GEMM1: qkv[t][d] = sum_c x[t][c] * Wqkv[d][c];  M=16384, N=3072, K=1024
// epilogue splits d into (part,h,hd); writes q*SCALE,k as [bh][n][hd] bf16,
// v transposed as [bh][hd][n] bf16 (8B packed stores: 4 consecutive tokens).
// ------------------------------------------------------------------
__global__ __launch_bounds__(256, 2)
void qkv_gemm(const float* __restrict__ X, const float* __restrict__ W,
              u16* __restrict__ qb, u16* __restrict__ kb, u16* __restrict__ vT)
{
  __shared__ u16 As[128 * 40];   // 128 rows x 32 k, stride 40 (80B) -> 2-way banks
  __shared__ u16 Bs[128 * 40];
  const int t = threadIdx.x;
  const int row0 = blockIdx.y * 128;   // token tile
  const int col0 = blockIdx.x * 128;   // d tile
  const int lane = t & 63, w = t >> 6;
  const int quad = lane >> 4, l16 = lane & 15;
  const int wm = w & 1, wn = w >> 1;

  f32x4 acc[4][4];
#pragma unroll
  for (int i = 0; i < 4; i++)
#pragma unroll
    for (int j = 0; j < 4; j++) acc[i][j] = f32x4{0.f, 0.f, 0.f, 0.f};

  // staging coords: chunk c = t + i*256 -> row=(t>>3)+32i, kc=t&7 (4 floats)
  const int rbase = t >> 3, kc = t & 7;
  const float* xa = X + (size_t)(row0 + rbase) * 1024 + kc * 4;
  const float* wb = W + (size_t)(col0 + rbase) * 1024 + kc * 4;
  char* asw = (char*)As + rbase * 80 + kc * 8;
  char* bsw = (char*)Bs + rbase * 80 + kc * 8;

  int aoff[4], boff[4];
#pragma unroll
  for (int mt = 0; mt < 4; mt++) aoff[mt] = (wm * 64 + mt * 16 + l16) * 80 + quad * 16;
#pragma unroll
  for (int nt = 0; nt < 4; nt++) boff[nt] = (wn * 64 + nt * 16 + l16) * 80 + quad * 16;

  for (int k0 = 0; k0 < 1024; k0 += 32) {
    __syncthreads();
#pragma unroll
    for (int i = 0; i < 4; i++) {
      float4 va = *(const float4*)(xa + k0 + (size_t)i * 32 * 1024);
      float4 vb = *(const float4*)(wb + k0 + (size_t)i * 32 * 1024);
      uint2 pa, pb;
      pa.x = f2b(va.x) | ((unsigned)f2b(va.y) << 16);
      pa.y = f2b(va.z) | ((unsigned)f2b(va.w) << 16);
      pb.x = f2b(vb.x) | ((unsigned)f2b(vb.y) << 16);
      pb.y = f2b(vb.z) | ((unsigned)f2b(vb.w) << 16);
      *(uint2*)(asw + i * 32 * 80) = pa;
      *(uint2*)(bsw + i * 32 * 80) = pb;
    }
    __syncthreads();
    bf16x8 af[4], bf[4];
#pragma unroll
    for (int mt = 0; mt < 4; mt++) af[mt] = *(const bf16x8*)((const char*)As + aoff[mt]);
#pragma unroll
    for (int nt = 0; nt < 4; nt++) bf[nt] = *(const bf16x8*)((const char*)Bs + boff[nt]);
#pragma unroll
    for (int mt = 0; mt < 4; mt++)
#pragma unroll
      for (int nt = 0; nt < 4; nt++)
        acc[mt][nt] = MFMA16(af[mt], bf[nt], acc[mt][nt]);
  }

  // epilogue
  const int tok_base = row0 + wm * 64;
#pragma unroll
  for (int nt = 0; nt < 4; nt++) {
    int d = col0 + wn * 64 + nt * 16;       // tile-uniform
    int part = d >> 10;
    int hh = (d >> 6) & 15;
    int hd = (d & 63) + l16;
    if (part == 2) {
#pragma unroll
      for (int mt = 0; mt < 4; mt++) {
        int nb = tok_base + mt * 16 + quad * 4;   // 4 consecutive tokens
        int bb = nb >> 9, nn = nb & 511;
        uint2 pk;
        pk.x = f2b(acc[mt][nt][0]) | ((unsigned)f2b(acc[mt][nt][1]) << 16);
        pk.y = f2b(acc[mt][nt][2]) | ((unsigned)f2b(acc[mt][nt][3]) << 16);
        *(uint2*)(vT + (((size_t)(bb * 16 + hh)) * 64 + hd) * 512 + nn) = pk;
      }
    } else {
      u16* dst = (part == 0) ? qb : kb;
      float sc = (part == 0) ? 0.125f : 1.0f;
#pragma unroll
      for (int mt = 0; mt < 4; mt++)
#pragma unroll
        for (int r = 0; r < 4; r++) {
          int tok = tok_base + mt * 16 + quad * 4 + r;
          int bb = tok >> 9, nn = tok & 511;
          dst[(((size_t)(bb * 16 + hh)) * 512 + nn) * 64 + hd] = f2b(acc[mt][nt][r] * sc);
        }
    }
  }
}

// ------------------------------------------------------------------
// Attention: per (bh, 128-row q tile). Flash-style over 4 key tiles of 128.
// Q frags from global; K tile + V^T tile staged in LDS; P LDS round-trip
// (wave-private, unioned with K region). Row mask bias dropped (softmax-
// invariant); col bias mask[b][key] added before softmax.
// ------------------------------------------------------------------
__global__ __launch_bounds__(256, 2)
void attn_kernel(const u16* __restrict__ qb, const u16* __restrict__ kb,
                 const u16* __restrict__ vT, const float* __restrict__ mask,
                 u16* __restrict__ ao)
{
  // LDS: [0,34816): K tile (128x72 u16 = 36864B? no: used 128*144B=18432) then P (4 waves x 32x136 u16 = 34816)
  //      [34816, 52224): V^T tile 64x136 u16
  //      [52224, 54272): mask row 512 f32
  __shared__ __align__(16) char lds[54272];
  u16* KT = (u16*)lds;                       // stride 72 elems (144B)
  float* mS = (float*)(lds + 52224);

  const int t = threadIdx.x;
  const int lane = t & 63, w = t >> 6, quad = lane >> 4, l16 = lane & 15;
  const int qt = blockIdx.x, bh = blockIdx.y, b = bh >> 4, hh = bh & 15;
  const u16* Qp = qb + (size_t)bh * 512 * 64;
  const u16* Kp = kb + (size_t)bh * 512 * 64;
  const u16* Vp = vT + (size_t)bh * 64 * 512;

  for (int i = t; i < 512; i += 256) mS[i] = mask[b * 512 + i];

  // Q fragments (wave-private rows)
  const int qrow_base = qt * 128 + w * 32;
  bf16x8 qf[2][2];
#pragma unroll
  for (int mt = 0; mt < 2; mt++)
#pragma unroll
    for (int ks = 0; ks < 2; ks++)
      qf[mt][ks] = *(const bf16x8*)(Qp + (size_t)(qrow_base + mt * 16 + l16) * 64 + ks * 32 + quad * 8);

  f32x4 oacc[2][4];
#pragma unroll
  for (int mt = 0; mt < 2; mt++)
#pragma unroll
    for (int ht = 0; ht < 4; ht++) oacc[mt][ht] = f32x4{0.f, 0.f, 0.f, 0.f};
  float mrun[2][4], lrun[2][4];
#pragma unroll
  for (int mt = 0; mt < 2; mt++)
#pragma unroll
    for (int r = 0; r < 4; r++) { mrun[mt][r] = -1e30f; lrun[mt][r] = 0.f; }

  // staging coords
  const int krow = t >> 3, khc = t & 7;    // K: key=(t>>3)+32i, hc 8-elem chunk
  const int vrow = t >> 4, vkc = t & 15;   // V^T: hd=(t>>4)+16i, kc 8-elem chunk

  for (int kt = 0; kt < 4; kt++) {
    __syncthreads();   // (A) prev P@V reads done
#pragma unroll
    for (int i = 0; i < 4; i++) {
      int key = krow + 32 * i;
      uint4 d4 = *(const uint4*)(Kp + (size_t)(kt * 128 + key) * 64 + khc * 8);
      *(uint4*)((char*)KT + key * 144 + khc * 16) = d4;
    }
    char* VT = lds + 34816;                 // stride 136 elems (272B)
#pragma unroll
    for (int i = 0; i < 4; i++) {
      int hd = vrow + 16 * i;
      uint4 d4 = *(const uint4*)(Vp + (size_t)hd * 512 + kt * 128 + vkc * 8);
      *(uint4*)(VT + hd * 272 + vkc * 16) = d4;
    }
    __syncthreads();   // (B) tiles visible

    // S = Q K^T  + col mask bias
    f32x4 s[2][8];
#pragma unroll
    for (int nt = 0; nt < 8; nt++) {
      const char* kr = (const char*)KT + (nt * 16 + l16) * 144 + quad * 16;
      bf16x8 kf0 = *(const bf16x8*)kr;
      bf16x8 kf1 = *(const bf16x8*)(kr + 64);
      float mv = mS[kt * 128 + nt * 16 + l16];
#pragma unroll
      for (int mt = 0; mt < 2; mt++) {
        f32x4 z = f32x4{0.f, 0.f, 0.f, 0.f};
        z = MFMA16(qf[mt][0], kf0, z);
        z = MFMA16(qf[mt][1], kf1, z);
#pragma unroll
        for (int r = 0; r < 4; r++) z[r] += mv;
        s[mt][nt] = z;
      }
    }

    // online softmax update (rows = mt*16 + quad*4 + r; replicated over l16)
    float alpha[2][4];
#pragma unroll
    for (int mt = 0; mt < 2; mt++)
#pragma unroll
      for (int r = 0; r < 4; r++) {
        float rm = s[mt][0][r];
#pragma unroll
        for (int nt = 1; nt < 8; nt++) rm = fmaxf(rm, s[mt][nt][r]);
        rm = fmaxf(rm, __shfl_xor(rm, 1));
        rm = fmaxf(rm, __shfl_xor(rm, 2));
        rm = fmaxf(rm, __shfl_xor(rm, 4));
        rm = fmaxf(rm, __shfl_xor(rm, 8));
        float mo = mrun[mt][r];
        float mn = fmaxf(mo, rm);
        float al = __expf(mo - mn);
        mrun[mt][r] = mn;
        float rs = 0.f;
#pragma unroll
        for (int nt = 0; nt < 8; nt++) {
          float p = __expf(s[mt][nt][r] - mn);
          s[mt][nt][r] = p;
          rs += p;
        }
        rs += __shfl_xor(rs, 1);
        rs += __shfl_xor(rs, 2);
        rs += __shfl_xor(rs, 4);
        rs += __shfl_xor(rs, 8);
        lrun[mt][r] = al * lrun[mt][r] + rs;
        alpha[mt][r] = al;
      }
#pragma unroll
    for (int mt = 0; mt < 2; mt++)
#pragma unroll
      for (int ht = 0; ht < 4; ht++)
#pragma unroll
        for (int r = 0; r < 4; r++) oacc[mt][ht][r] *= alpha[mt][r];

    __syncthreads();   // (C) all waves done reading K tile -> safe to overwrite with P
    char* Pw = lds + w * 8704;              // wave-private 32x136 u16 (stride 272B)
#pragma unroll
    for (int mt = 0; mt < 2; mt++)
#pragma unroll
      for (int nt = 0; nt < 8; nt++)
#pragma unroll
        for (int r = 0; r < 4; r++)
          *(u16*)(Pw + (mt * 16 + quad * 4 + r) * 272 + (nt * 16 + l16) * 2) = f2b(s[mt][nt][r]);
    __syncthreads();   // (D) P visible (incl. lgkmcnt drain)

    // O += P V
    bf16x8 pf[2][4];
#pragma unroll
    for (int mt = 0; mt < 2; mt++)
#pragma unroll
      for (int ks = 0; ks < 4; ks++)
        pf[mt][ks] = *(const bf16x8*)(Pw + (mt * 16 + l16) * 272 + ks * 64 + quad * 16);
#pragma unroll
    for (int ht = 0; ht < 4; ht++)
#pragma unroll
      for (int ks = 0; ks < 4; ks++) {
        bf16x8 vf = *(const bf16x8*)(VT + (ht * 16 + l16) * 272 + ks * 64 + quad * 16);
#pragma unroll
        for (int mt = 0; mt < 2; mt++)
          oacc[mt][ht] = MFMA16(pf[mt][ks], vf, oacc[mt][ht]);
      }
  }

  // epilogue: ao[b*512+n][h*64+hd] bf16
#pragma unroll
  for (int mt = 0; mt < 2; mt++)
#pragma unroll
    for (int r = 0; r < 4; r++) {
      float inv = 1.0f / lrun[mt][r];
      int n = qrow_base + mt * 16 + quad * 4 + r;
#pragma unroll
      for (int ht = 0; ht < 4; ht++) {
        int c = hh * 64 + ht * 16 + l16;
        ao[((size_t)(b * 512 + n)) * 1024 + c] = f2b(oacc[mt][ht][r] * inv);
      }
    }
}

// ------------------------------------------------------------------
// GEMM2: out[t][d] = sum_c ao[t][c] * Wproj[d][c] + bias[d]; fp32 out
// ------------------------------------------------------------------
__global__ __launch_bounds__(256, 2)
void proj_gemm(const u16* __restrict__ A, const float* __restrict__ W,
               const float* __restrict__ bias, float* __restrict__ out)
{
  __shared__ u16 As[128 * 40];
  __shared__ u16 Bs[128 * 40];
  const int t = threadIdx.x;
  const int row0 = blockIdx.y * 128;
  const int col0 = blockIdx.x * 128;
  const int lane = t & 63, w = t >> 6;
  const int quad = lane >> 4, l16 = lane & 15;
  const int wm = w & 1, wn = w >> 1;

  f32x4 acc[4][4];
#pragma unroll
  for (int i = 0; i < 4; i++)
#pragma unroll
    for (int j = 0; j < 4; j++) acc[i][j] = f32x4{0.f, 0.f, 0.f, 0.f};

  const int rbase = t >> 3, kc = t & 7;
  const u16* aa = A + (size_t)(row0 + rbase) * 1024 + kc * 4;
  const float* wb = W + (size_t)(col0 + rbase) * 1024 + kc * 4;
  char* asw = (char*)As + rbase * 80 + kc * 8;
  char* bsw = (char*)Bs + rbase * 80 + kc * 8;

  int aoff[4], boff[4];
#pragma unroll
  for (int mt = 0; mt < 4; mt++) aoff[mt] = (wm * 64 + mt * 16 + l16) * 80 + quad * 16;
#pragma unroll
  for (int nt = 0; nt < 4; nt++) boff[nt] = (wn * 64 + nt * 16 + l16) * 80 + quad * 16;

  for (int k0 = 0; k0 < 1024; k0 += 32) {
    __syncthreads();
#pragma unroll
    for (int i = 0; i < 4; i++) {
      uint2 pa = *(const uint2*)(aa + k0 + (size_t)i * 32 * 1024);  // 4 bf16
      float4 vb = *(const float4*)(wb + k0 + (size_t)i * 32 * 1024);
      uint2 pb;
      pb.x = f2b(vb.x) | ((unsigned)f2b(vb.y) << 16);
      pb.y = f2b(vb.z) | ((unsigned)f2b(vb.w) << 16);
      *(uint2*)(asw + i * 32 * 80) = pa;
      *(uint2*)(bsw + i * 32 * 80) = pb;
    }
    __syncthreads();
    bf16x8 af[4], bf[4];
#pragma unroll
    for (int mt = 0; mt < 4; mt++) af[mt] = *(const bf16x8*)((const char*)As + aoff[mt]);
#pragma unroll
    for (int nt = 0; nt < 4; nt++) bf[nt] = *(const bf16x8*)((const char*)Bs + boff[nt]);
#pragma unroll
    for (int mt = 0; mt < 4; mt++)
#pragma unroll
      for (int nt = 0; nt < 4; nt++)
        acc[mt][nt] = MFMA16(af[mt], bf[nt], acc[mt][nt]);
  }

  const int tok_base = row0 + wm * 64;
#pragma unroll
  for (int nt = 0; nt < 4; nt++) {
    int d = col0 + wn * 64 + nt * 16 + l16;
    float bv = bias[d];
#pragma unroll
    for (int mt = 0; mt < 4; mt++)
#pragma unroll
      for (int r = 0; r < 4; r++) {
        int tok = tok_base + mt * 16 + quad * 4 + r;
        out[(size_t)tok * 1024 + d] = acc[mt][nt][r] + bv;
      }
  }
}

extern "C" void kernel_launch(void* const* d_in, const int* in_sizes, int n_in,
                              void* d_out, int out_size, void* d_ws, size_t ws_size,
                              hipStream_t stream) {
  const float* x     = (const float*)d_in[0];
  const float* mask  = (const float*)d_in[1];
  const float* Wqkv  = (const float*)d_in[2];
  const float* Wproj = (const float*)d_in[3];
  const float* bproj = (const float*)d_in[4];
  float* out = (float*)d_out;

  // ws carve: 4 x 16.78M bf16 = 134.2 MB
  u16* qb = (u16*)d_ws;
  u16* kb = qb + 16777216;
  u16* vT = kb + 16777216;
  u16* ao = vT + 16777216;

  qkv_gemm<<<dim3(24, 128), 256, 0, stream>>>(x, Wqkv, qb, kb, vT);
  attn_kernel<<<dim3(4, 512), 256, 0, stream>>>(qb, kb, vT, mask, ao);
  proj_gemm<<<dim3(8, 128), 256, 0, stream>>>(ao, Wproj, bproj, out);
}

// Round 3
// 434.153 us; speedup vs baseline: 1.5494x; 1.5494x over previous
//
#include <hip/hip_runtime.h>
#include <stdint.h>

typedef unsigned short u16;
typedef __bf16 bf16x8 __attribute__((ext_vector_type(8)));
typedef float  f32x4  __attribute__((ext_vector_type(4)));

#define MFMA16(a,b,c) __builtin_amdgcn_mfma_f32_16x16x32_bf16((a),(b),(c),0,0,0)

// B=32, N=512, C=1024, H=16, HD=64; SCALE = 1/8
__device__ __forceinline__ u16 f2b(float f) {
  unsigned int u = __builtin_bit_cast(unsigned int, f);
  u += 0x7fffu + ((u >> 16) & 1u);
  return (u16)(u >> 16);
}

// async 16B global->LDS (lds dest must be wave-uniform; lane i lands at l + i*16)
__device__ __forceinline__ void gll16(const u16* g, u16* l) {
  __builtin_amdgcn_global_load_lds((const __attribute__((address_space(1))) unsigned int*)g,
                                   (__attribute__((address_space(3))) unsigned int*)l,
                                   16, 0, 0);
}

// ------------------------------------------------------------------
// cvt_all: fp32 -> bf16 for x (16.78M), W_qkv (3.15M), W_proj (1.05M)
// float4 per thread; region boundaries are multiples of 256 threads.
// ------------------------------------------------------------------
__global__ __launch_bounds__(256)
void cvt_all(const float* __restrict__ X, const float* __restrict__ Wq,
             const float* __restrict__ Wp, u16* __restrict__ Xb,
             u16* __restrict__ Wqb, u16* __restrict__ Wpb)
{
  size_t i = (size_t)blockIdx.x * 256 + threadIdx.x;   // float4 index
  const float* src; u16* dst; size_t off;
  if (i < 4194304)       { src = X;  dst = Xb;  off = i; }
  else if (i < 4980736)  { src = Wq; dst = Wqb; off = i - 4194304; }
  else                   { src = Wp; dst = Wpb; off = i - 4980736; }
  float4 v = ((const float4*)src)[off];
  uint2 p;
  p.x = f2b(v.x) | ((unsigned)f2b(v.y) << 16);
  p.y = f2b(v.z) | ((unsigned)f2b(v.w) << 16);
  ((uint2*)dst)[off] = p;
}

// ------------------------------------------------------------------
// GEMM1 (m97 structure): qkv[t][d] = sum_c Xb[t][c] * Wb[d][c]
// M=16384, N=3072, K=1024. 128x128 tile, BK=32, global_load_lds width16,
// XOR-swizzled k-slot (slot = kpart ^ ((row>>1)&3)) -> 2-way LDS reads.
// Epilogue: q*SCALE,k as [bh][n][hd] bf16; v transposed [bh][hd][n] bf16.
// ------------------------------------------------------------------
__global__ __launch_bounds__(256, 2)
void qkv_gemm(const u16* __restrict__ Xb, const u16* __restrict__ Wb,
              u16* __restrict__ qb, u16* __restrict__ kb, u16* __restrict__ vT)
{
  __shared__ u16 As[128 * 32];
  __shared__ u16 Bs[128 * 32];
  const int t = threadIdx.x;
  const int row0 = blockIdx.y * 128;   // token tile
  const int col0 = blockIdx.x * 128;   // d tile
  const int lane = t & 63, w = t >> 6;
  const int quad = lane >> 4, l16 = lane & 15;
  const int wm = w & 1, wn = w >> 1;

  f32x4 acc[4][4];
#pragma unroll
  for (int i = 0; i < 4; i++)
#pragma unroll
    for (int j = 0; j < 4; j++) acc[i][j] = f32x4{0.f, 0.f, 0.f, 0.f};

  // staging: wave w stages rows [w*32, (w+1)*32) of both tiles, 2 chunks of 16 rows.
  // lane i: row = chunk_base + (i>>2); global kpart = (i&3) ^ ((i>>3)&3)
  const int srow = lane >> 2;
  const int kpart = (lane & 3) ^ ((lane >> 3) & 3);
  const u16* ga[2]; const u16* gb[2];
  u16* la[2]; u16* lb[2];
#pragma unroll
  for (int j = 0; j < 2; j++) {
    int r = w * 32 + j * 16 + srow;
    ga[j] = Xb + (size_t)(row0 + r) * 1024 + kpart * 8;
    gb[j] = Wb + (size_t)(col0 + r) * 1024 + kpart * 8;
    la[j] = As + (w * 2 + j) * 512;   // wave-uniform chunk base (1024B chunks)
    lb[j] = Bs + (w * 2 + j) * 512;
  }

  // fragment byte offsets (swizzled): row r, k-quad q -> r*64 + (q^((r>>1)&3))*16
  int aoff[4], boff[4];
#pragma unroll
  for (int mt = 0; mt < 4; mt++) { int r = wm * 64 + mt * 16 + l16; aoff[mt] = r * 64 + ((quad ^ ((r >> 1) & 3)) * 16); }
#pragma unroll
  for (int nt = 0; nt < 4; nt++) { int r = wn * 64 + nt * 16 + l16; boff[nt] = r * 64 + ((quad ^ ((r >> 1) & 3)) * 16); }

  for (int k0 = 0; k0 < 1024; k0 += 32) {
    __syncthreads();
#pragma unroll
    for (int j = 0; j < 2; j++) {
      gll16(ga[j] + k0, la[j]);
      gll16(gb[j] + k0, lb[j]);
    }
    __syncthreads();
    bf16x8 af[4], bfr[4];
#pragma unroll
    for (int mt = 0; mt < 4; mt++) af[mt] = *(const bf16x8*)((const char*)As + aoff[mt]);
#pragma unroll
    for (int nt = 0; nt < 4; nt++) bfr[nt] = *(const bf16x8*)((const char*)Bs + boff[nt]);
#pragma unroll
    for (int mt = 0; mt < 4; mt++)
#pragma unroll
      for (int nt = 0; nt < 4; nt++)
        acc[mt][nt] = MFMA16(af[mt], bfr[nt], acc[mt][nt]);
  }

  // epilogue (verified round 1)
  const int tok_base = row0 + wm * 64;
#pragma unroll
  for (int nt = 0; nt < 4; nt++) {
    int d = col0 + wn * 64 + nt * 16;       // tile-uniform
    int part = d >> 10;
    int hh = (d >> 6) & 15;
    int hd = (d & 63) + l16;
    if (part == 2) {
#pragma unroll
      for (int mt = 0; mt < 4; mt++) {
        int nb = tok_base + mt * 16 + quad * 4;   // 4 consecutive tokens
        int bb = nb >> 9, nn = nb & 511;
        uint2 pk;
        pk.x = f2b(acc[mt][nt][0]) | ((unsigned)f2b(acc[mt][nt][1]) << 16);
        pk.y = f2b(acc[mt][nt][2]) | ((unsigned)f2b(acc[mt][nt][3]) << 16);
        *(uint2*)(vT + (((size_t)(bb * 16 + hh)) * 64 + hd) * 512 + nn) = pk;
      }
    } else {
      u16* dst = (part == 0) ? qb : kb;
      float sc = (part == 0) ? 0.125f : 1.0f;
#pragma unroll
      for (int mt = 0; mt < 4; mt++)
#pragma unroll
        for (int r = 0; r < 4; r++) {
          int tok = tok_base + mt * 16 + quad * 4 + r;
          int bb = tok >> 9, nn = tok & 511;
          dst[(((size_t)(bb * 16 + hh)) * 512 + nn) * 64 + hd] = f2b(acc[mt][nt][r] * sc);
        }
    }
  }
}

// ------------------------------------------------------------------
// Attention: flash-style per (bh, 128-row q tile); round-1 verified logic,
// VT pointer hoisted to fix the redefinition.
// ------------------------------------------------------------------
__global__ __launch_bounds__(256, 2)
void attn_kernel(const u16* __restrict__ qb, const u16* __restrict__ kb,
                 const u16* __restrict__ vT, const float* __restrict__ mask,
                 u16* __restrict__ ao)
{
  __shared__ __align__(16) char lds[54272];
  u16* KT = (u16*)lds;                       // stride 72 elems (144B)
  char* VT = lds + 34816;                    // V^T tile 64x136 u16 (272B stride)
  float* mS = (float*)(lds + 52224);

  const int t = threadIdx.x;
  const int lane = t & 63, w = t >> 6, quad = lane >> 4, l16 = lane & 15;
  const int qt = blockIdx.x, bh = blockIdx.y, b = bh >> 4, hh = bh & 15;
  const u16* Qp = qb + (size_t)bh * 512 * 64;
  const u16* Kp = kb + (size_t)bh * 512 * 64;
  const u16* Vp = vT + (size_t)bh * 64 * 512;

  for (int i = t; i < 512; i += 256) mS[i] = mask[b * 512 + i];

  const int qrow_base = qt * 128 + w * 32;
  bf16x8 qf[2][2];
#pragma unroll
  for (int mt = 0; mt < 2; mt++)
#pragma unroll
    for (int ks = 0; ks < 2; ks++)
      qf[mt][ks] = *(const bf16x8*)(Qp + (size_t)(qrow_base + mt * 16 + l16) * 64 + ks * 32 + quad * 8);

  f32x4 oacc[2][4];
#pragma unroll
  for (int mt = 0; mt < 2; mt++)
#pragma unroll
    for (int ht = 0; ht < 4; ht++) oacc[mt][ht] = f32x4{0.f, 0.f, 0.f, 0.f};
  float mrun[2][4], lrun[2][4];
#pragma unroll
  for (int mt = 0; mt < 2; mt++)
#pragma unroll
    for (int r = 0; r < 4; r++) { mrun[mt][r] = -1e30f; lrun[mt][r] = 0.f; }

  const int krow = t >> 3, khc = t & 7;
  const int vrow = t >> 4, vkc = t & 15;

  for (int kt = 0; kt < 4; kt++) {
    __syncthreads();
#pragma unroll
    for (int i = 0; i < 4; i++) {
      int key = krow + 32 * i;
      uint4 d4 = *(const uint4*)(Kp + (size_t)(kt * 128 + key) * 64 + khc * 8);
      *(uint4*)((char*)KT + key * 144 + khc * 16) = d4;
    }
#pragma unroll
    for (int i = 0; i < 4; i++) {
      int hd = vrow + 16 * i;
      uint4 d4 = *(const uint4*)(Vp + (size_t)hd * 512 + kt * 128 + vkc * 8);
      *(uint4*)(VT + hd * 272 + vkc * 16) = d4;
    }
    __syncthreads();

    f32x4 s[2][8];
#pragma unroll
    for (int nt = 0; nt < 8; nt++) {
      const char* kr = (const char*)KT + (nt * 16 + l16) * 144 + quad * 16;
      bf16x8 kf0 = *(const bf16x8*)kr;
      bf16x8 kf1 = *(const bf16x8*)(kr + 64);
      float mv = mS[kt * 128 + nt * 16 + l16];
#pragma unroll
      for (int mt = 0; mt < 2; mt++) {
        f32x4 z = f32x4{0.f, 0.f, 0.f, 0.f};
        z = MFMA16(qf[mt][0], kf0, z);
        z = MFMA16(qf[mt][1], kf1, z);
#pragma unroll
        for (int r = 0; r < 4; r++) z[r] += mv;
        s[mt][nt] = z;
      }
    }

    float alpha[2][4];
#pragma unroll
    for (int mt = 0; mt < 2; mt++)
#pragma unroll
      for (int r = 0; r < 4; r++) {
        float rm = s[mt][0][r];
#pragma unroll
        for (int nt = 1; nt < 8; nt++) rm = fmaxf(rm, s[mt][nt][r]);
        rm = fmaxf(rm, __shfl_xor(rm, 1));
        rm = fmaxf(rm, __shfl_xor(rm, 2));
        rm = fmaxf(rm, __shfl_xor(rm, 4));
        rm = fmaxf(rm, __shfl_xor(rm, 8));
        float mo = mrun[mt][r];
        float mn = fmaxf(mo, rm);
        float al = __expf(mo - mn);
        mrun[mt][r] = mn;
        float rs = 0.f;
#pragma unroll
        for (int nt = 0; nt < 8; nt++) {
          float p = __expf(s[mt][nt][r] - mn);
          s[mt][nt][r] = p;
          rs += p;
        }
        rs += __shfl_xor(rs, 1);
        rs += __shfl_xor(rs, 2);
        rs += __shfl_xor(rs, 4);
        rs += __shfl_xor(rs, 8);
        lrun[mt][r] = al * lrun[mt][r] + rs;
        alpha[mt][r] = al;
      }
#pragma unroll
    for (int mt = 0; mt < 2; mt++)
#pragma unroll
      for (int ht = 0; ht < 4; ht++)
#pragma unroll
        for (int r = 0; r < 4; r++) oacc[mt][ht][r] *= alpha[mt][r];

    __syncthreads();
    char* Pw = lds + w * 8704;
#pragma unroll
    for (int mt = 0; mt < 2; mt++)
#pragma unroll
      for (int nt = 0; nt < 8; nt++)
#pragma unroll
        for (int r = 0; r < 4; r++)
          *(u16*)(Pw + (mt * 16 + quad * 4 + r) * 272 + (nt * 16 + l16) * 2) = f2b(s[mt][nt][r]);
    __syncthreads();

    bf16x8 pf[2][4];
#pragma unroll
    for (int mt = 0; mt < 2; mt++)
#pragma unroll
      for (int ks = 0; ks < 4; ks++)
        pf[mt][ks] = *(const bf16x8*)(Pw + (mt * 16 + l16) * 272 + ks * 64 + quad * 16);
#pragma unroll
    for (int ht = 0; ht < 4; ht++)
#pragma unroll
      for (int ks = 0; ks < 4; ks++) {
        bf16x8 vf = *(const bf16x8*)(VT + (ht * 16 + l16) * 272 + ks * 64 + quad * 16);
#pragma unroll
        for (int mt = 0; mt < 2; mt++)
          oacc[mt][ht] = MFMA16(pf[mt][ks], vf, oacc[mt][ht]);
      }
  }

#pragma unroll
  for (int mt = 0; mt < 2; mt++)
#pragma unroll
    for (int r = 0; r < 4; r++) {
      float inv = 1.0f / lrun[mt][r];
      int n = qrow_base + mt * 16 + quad * 4 + r;
#pragma unroll
      for (int ht = 0; ht < 4; ht++) {
        int c = hh * 64 + ht * 16 + l16;
        ao[((size_t)(b * 512 + n)) * 1024 + c] = f2b(oacc[mt][ht][r] * inv);
      }
    }
}

// ------------------------------------------------------------------
// GEMM2 (m97 structure): out[t][d] = sum_c ao[t][c]*Wpb[d][c] + bias[d]
// ------------------------------------------------------------------
__global__ __launch_bounds__(256, 2)
void proj_gemm(const u16* __restrict__ A, const u16* __restrict__ Wb,
               const float* __restrict__ bias, float* __restrict__ out)
{
  __shared__ u16 As[128 * 32];
  __shared__ u16 Bs[128 * 32];
  const int t = threadIdx.x;
  const int row0 = blockIdx.y * 128;
  const int col0 = blockIdx.x * 128;
  const int lane = t & 63, w = t >> 6;
  const int quad = lane >> 4, l16 = lane & 15;
  const int wm = w & 1, wn = w >> 1;

  f32x4 acc[4][4];
#pragma unroll
  for (int i = 0; i < 4; i++)
#pragma unroll
    for (int j = 0; j < 4; j++) acc[i][j] = f32x4{0.f, 0.f, 0.f, 0.f};

  const int srow = lane >> 2;
  const int kpart = (lane & 3) ^ ((lane >> 3) & 3);
  const u16* ga[2]; const u16* gb[2];
  u16* la[2]; u16* lb[2];
#pragma unroll
  for (int j = 0; j < 2; j++) {
    int r = w * 32 + j * 16 + srow;
    ga[j] = A  + (size_t)(row0 + r) * 1024 + kpart * 8;
    gb[j] = Wb + (size_t)(col0 + r) * 1024 + kpart * 8;
    la[j] = As + (w * 2 + j) * 512;
    lb[j] = Bs + (w * 2 + j) * 512;
  }

  int aoff[4], boff[4];
#pragma unroll
  for (int mt = 0; mt < 4; mt++) { int r = wm * 64 + mt * 16 + l16; aoff[mt] = r * 64 + ((quad ^ ((r >> 1) & 3)) * 16); }
#pragma unroll
  for (int nt = 0; nt < 4; nt++) { int r = wn * 64 + nt * 16 + l16; boff[nt] = r * 64 + ((quad ^ ((r >> 1) & 3)) * 16); }

  for (int k0 = 0; k0 < 1024; k0 += 32) {
    __syncthreads();
#pragma unroll
    for (int j = 0; j < 2; j++) {
      gll16(ga[j] + k0, la[j]);
      gll16(gb[j] + k0, lb[j]);
    }
    __syncthreads();
    bf16x8 af[4], bfr[4];
#pragma unroll
    for (int mt = 0; mt < 4; mt++) af[mt] = *(const bf16x8*)((const char*)As + aoff[mt]);
#pragma unroll
    for (int nt = 0; nt < 4; nt++) bfr[nt] = *(const bf16x8*)((const char*)Bs + boff[nt]);
#pragma unroll
    for (int mt = 0; mt < 4; mt++)
#pragma unroll
      for (int nt = 0; nt < 4; nt++)
        acc[mt][nt] = MFMA16(af[mt], bfr[nt], acc[mt][nt]);
  }

  const int tok_base = row0 + wm * 64;
#pragma unroll
  for (int nt = 0; nt < 4; nt++) {
    int d = col0 + wn * 64 + nt * 16 + l16;
    float bv = bias[d];
#pragma unroll
    for (int mt = 0; mt < 4; mt++)
#pragma unroll
      for (int r = 0; r < 4; r++) {
        int tok = tok_base + mt * 16 + quad * 4 + r;
        out[(size_t)tok * 1024 + d] = acc[mt][nt][r] + bv;
      }
  }
}

extern "C" void kernel_launch(void* const* d_in, const int* in_sizes, int n_in,
                              void* d_out, int out_size, void* d_ws, size_t ws_size,
                              hipStream_t stream) {
  const float* x     = (const float*)d_in[0];
  const float* mask  = (const float*)d_in[1];
  const float* Wqkv  = (const float*)d_in[2];
  const float* Wproj = (const float*)d_in[3];
  const float* bproj = (const float*)d_in[4];
  float* out = (float*)d_out;

  // ws carve (u16 elems): qb|kb|vT|{Xb then ao}|Wqb|Wpb  = 142.6 MB total
  u16* qb  = (u16*)d_ws;
  u16* kb  = qb + 16777216;
  u16* vT  = kb + 16777216;
  u16* XbAo = vT + 16777216;     // Xb during qkv_gemm; ao afterwards (x dead)
  u16* Wqb = XbAo + 16777216;
  u16* Wpb = Wqb + 3145728;

  cvt_all<<<20480, 256, 0, stream>>>(x, Wqkv, Wproj, XbAo, Wqb, Wpb);
  qkv_gemm<<<dim3(24, 128), 256, 0, stream>>>(XbAo, Wqb, qb, kb, vT);
  attn_kernel<<<dim3(4, 512), 256, 0, stream>>>(qb, kb, vT, mask, XbAo);
  proj_gemm<<<dim3(8, 128), 256, 0, stream>>>(XbAo, Wpb, bproj, out);
}